// Round 1
// baseline (293.426 us; speedup 1.0000x reference)
//
#include <hip/hip_runtime.h>

#define DIM 256
#define KCODES 1024
#define LEVELS 4
#define CHUNK 64
#define NCHUNK 16
#define TOKB 128                 // tokens per block (2 waves x 64)
#define NTOK 65536
#define NELEM (NTOK * DIM)

typedef _Float16 h8 __attribute__((ext_vector_type(8)));
typedef _Float16 h4 __attribute__((ext_vector_type(4)));
typedef _Float16 h2 __attribute__((ext_vector_type(2)));
typedef float f4 __attribute__((ext_vector_type(4)));
typedef float fx16 __attribute__((ext_vector_type(16)));
typedef unsigned int u32;

__device__ __forceinline__ void gload16(const void* g, void* l) {
  __builtin_amdgcn_global_load_lds(
      (const __attribute__((address_space(1))) void*)g,
      (__attribute__((address_space(3))) void*)l, 16, 0, 0);
}

// r2 accumulate over an h8 (v_dot2_f32_f16 when available: 4 instr vs 16)
__device__ __forceinline__ float sq8(h8 r, float acc) {
#if __has_builtin(__builtin_amdgcn_fdot2)
  #pragma unroll
  for (int j = 0; j < 4; ++j) {
    h2 p = {r[2 * j], r[2 * j + 1]};
    acc = __builtin_amdgcn_fdot2(p, p, acc, false);
  }
#else
  #pragma unroll
  for (int j = 0; j < 8; ++j) { float v = (float)r[j]; acc += v * v; }
#endif
  return acc;
}

// Phase 0: cb fp32 -> fp16; e2p = 0.25 - 0.5*||e||^2 (the +0.25 shift keeps all
// MFMA scores positive so raw float bits are unsigned-order-monotone -> 2-op
// argmax tracker). Also zeroes the commit accumulator (out is re-poisoned by
// the harness before every call).
__global__ __launch_bounds__(256) void rvq_prep(const float* __restrict__ cb,
                                                _Float16* __restrict__ cb16,
                                                float* __restrict__ e2p,
                                                float* __restrict__ out) {
  if (blockIdx.x == 0 && threadIdx.x == 0) out[NELEM] = 0.0f;
  const int row = blockIdx.x * 4 + (threadIdx.x >> 6);
  const int lane = threadIdx.x & 63;
  const float* src = cb + (size_t)row * DIM + lane * 4;
  f4 v = *(const f4*)src;
  h4 hv;
  hv[0] = (_Float16)v[0]; hv[1] = (_Float16)v[1];
  hv[2] = (_Float16)v[2]; hv[3] = (_Float16)v[3];
  *(h4*)(cb16 + (size_t)row * DIM + lane * 4) = hv;
  float s = v[0]*v[0] + v[1]*v[1] + v[2]*v[2] + v[3]*v[3];
  #pragma unroll
  for (int off = 32; off; off >>= 1) s += __shfl_xor(s, off, 64);
  if (lane == 0) e2p[row] = 0.25f - 0.5f * s;
}

// Main fused RVQ. Block = 2 waves; wave owns 64 tokens (2 m-tiles of 32) using
// v_mfma_f32_32x32x16_f16: each 16B B-frag LDS read feeds 2 MFMAs totalling
// 16 CU-cyc of matrix work vs ~12 cyc of LDS-read -> MFMA-bound (was LDS-bound
// at 2 MFMAs of 16x16x32 per read). B-tile LDS traffic halves vs the 32-tok/
// wave version. Residual lives only as fp16 A-frags (af[2][16], 128 VGPRs).
// LDS codebook chunks are DOUBLE-BUFFERED: one barrier per chunk; the
// global_load_lds for chunk g+1 is issued right after the barrier and drains
// at the NEXT barrier (a full compute phase later) -> no vmcnt stall. Chunks
// are contiguous across levels in cb16, so prefetch covers level boundaries.
__global__ __launch_bounds__(128, 1) void rvq_main(
    const float* __restrict__ x, const float* __restrict__ cb32,
    const _Float16* __restrict__ cb16, const float* __restrict__ e2p,
    float* __restrict__ out) {
  __shared__ __attribute__((aligned(16))) _Float16 clds[2][CHUNK * DIM];  // 64 KB
  __shared__ __attribute__((aligned(16))) float e2_lds[KCODES];           // 4 KB
  __shared__ __attribute__((aligned(16))) int idx_hist[TOKB][4];          // 2 KB
  __shared__ float r2_sh[TOKB];
  __shared__ float csum_sh[2];

  const int tid = threadIdx.x;
  const int wave = tid >> 6, lane = tid & 63;
  const int Llo = lane & 31, Lhi = lane >> 5;

  // Staging (per wave: 32 rows of the 64-row chunk, 16 gload16 calls):
  // call i covers rows wave*32 + 2i (+Lhi); lane fills row position p = Llo
  // with global granule g = p ^ (row&7)  (16B-granule XOR swizzle, self-inverse).
  // Period-4 in i: s4[j] + (i>>2)*4096 reproduces the full offset.
  // Read side: granule g = 2*kk + Lhi at row nt*32+Llo -> position g ^ (Llo&7);
  // period-4 in kk: rd4[u] + (kk>>2)*128.
  int s4[4], rd4[4];
  #pragma unroll
  for (int j = 0; j < 4; ++j) {
    const int key = (2 * j + Lhi) & 7;
    s4[j] = (wave * 32 + 2 * j + Lhi) * 512 + ((Llo ^ key) << 4);
    rd4[j] = (key ^ (Llo & 7)) << 4;
  }

  const char* cb16b = (const char*)cb16;
  // issue chunk 0 staging immediately; it flies during the x-init loads
  {
    char* ldst = (char*)&clds[0][0] + wave * 16384;
    #pragma unroll
    for (int i = 0; i < 16; ++i)
      gload16(cb16b + s4[i & 3] + (i >> 2) * 4096, ldst + i * 1024);
  }

  // ---- init: x -> fp16 A-frags + r2 partials ----
  // A-frag layout for 32x32x16: lane holds A[row=Llo][k = kk*16 + Lhi*8 + j].
  h8 af[2][16];
  float r2p[2] = {0.f, 0.f};
  const size_t tok0 = (size_t)blockIdx.x * TOKB + wave * 64;
  #pragma unroll
  for (int mt = 0; mt < 2; ++mt) {
    const float* xr = x + (tok0 + mt * 32 + Llo) * DIM + Lhi * 8;
    #pragma unroll
    for (int kk = 0; kk < 16; ++kk) {
      f4 a = *(const f4*)(xr + kk * 16);
      f4 b = *(const f4*)(xr + kk * 16 + 4);
      h8 h;
      #pragma unroll
      for (int j = 0; j < 4; ++j) { h[j] = (_Float16)a[j]; h[4 + j] = (_Float16)b[j]; }
      af[mt][kk] = h;
      r2p[mt] = sq8(h, r2p[mt]);
    }
  }

  float commit_acc = 0.f;

  for (int lvl = 0; lvl < LEVELS; ++lvl) {
    // pre-update residual norms -> LDS (wave-local slots; commit identity)
    #pragma unroll
    for (int mt = 0; mt < 2; ++mt) {
      float s = r2p[mt] + __shfl_xor(r2p[mt], 32, 64);
      if (Lhi == 0) r2_sh[wave * 64 + mt * 32 + Llo] = s;
    }
    // this level's shifted-e2 table (prev level's readers done: post-idx barrier)
    *(f4*)&e2_lds[tid * 8] = *(const f4*)(e2p + (lvl << 10) + tid * 8);
    *(f4*)&e2_lds[tid * 8 + 4] = *(const f4*)(e2p + (lvl << 10) + tid * 8 + 4);

    u32 best[2][16];
    #pragma unroll
    for (int mt = 0; mt < 2; ++mt)
      #pragma unroll
      for (int i = 0; i < 16; ++i) best[mt][i] = 0u;

    for (int c = 0; c < NCHUNK; ++c) {
      __syncthreads();  // staging of chunk g (issued a full phase ago) visible
      {
        // prefetch chunk g+1 into the other buffer (contiguous across levels;
        // clamp keeps the last iteration in-bounds, write is harmless)
        const int gn = lvl * NCHUNK + c + 1;
        const char* gsrc = cb16b + ((size_t)(gn < 64 ? gn : 63) << 15);
        char* ldst = (char*)&clds[(c + 1) & 1][0] + wave * 16384;
        #pragma unroll
        for (int i = 0; i < 16; ++i)
          gload16(gsrc + s4[i & 3] + (i >> 2) * 4096, ldst + i * 1024);
      }

      const char* cbuf = (const char*)&clds[c & 1][0];
      #pragma unroll
      for (int nt = 0; nt < 2; ++nt) {
        const int code0 = c * 64 + nt * 32;
        const float e2v = e2_lds[code0 + Llo];  // 0.25 - ||e||^2/2
        fx16 acc0, acc1;
        #pragma unroll
        for (int i = 0; i < 16; ++i) { acc0[i] = e2v; acc1[i] = e2v; }
        const char* bptr = cbuf + (nt * 32 + Llo) * 512;
        #pragma unroll
        for (int kk = 0; kk < 16; ++kk) {
          h8 b = *(const h8*)(bptr + rd4[kk & 3] + (kk >> 2) * 128);
          acc0 = __builtin_amdgcn_mfma_f32_32x32x16_f16(af[0][kk], b, acc0, 0, 0, 0);
          acc1 = __builtin_amdgcn_mfma_f32_32x32x16_f16(af[1][kk], b, acc1, 0, 0, 0);
        }
        // scores all positive -> raw bits unsigned-monotone; pack
        // (bits & ~1023) | (1023-code): umax == argmax, smaller-index ties
        const u32 invc = ((u32)(code0 + Llo)) ^ 1023u;
        #pragma unroll
        for (int i = 0; i < 16; ++i) {
          u32 p0 = (__float_as_uint(acc0[i]) & 0xFFFFFC00u) | invc;
          if (p0 > best[0][i]) best[0][i] = p0;
          u32 p1 = (__float_as_uint(acc1[i]) & 0xFFFFFC00u) | invc;
          if (p1 > best[1][i]) best[1][i] = p1;
        }
      }
    }

    // reduce best across the 32 column (code) lanes
    #pragma unroll
    for (int mt = 0; mt < 2; ++mt)
      #pragma unroll
      for (int i = 0; i < 16; ++i) {
        u32 b = best[mt][i];
        #pragma unroll
        for (int off = 1; off < 32; off <<= 1) {
          u32 o = __shfl_xor(b, off, 32);
          if (o > b) b = o;
        }
        best[mt][i] = b;
      }

    if (Llo == 0) {
      // C/D layout 32x32: col=Llo, row=(i&3)+8*(i>>2)+4*Lhi
      #pragma unroll
      for (int mt = 0; mt < 2; ++mt)
        #pragma unroll
        for (int i = 0; i < 16; ++i) {
          const u32 p = best[mt][i];
          const int code = (int)((p & 1023u) ^ 1023u);
          const int t = wave * 64 + mt * 32 + (i & 3) + 8 * (i >> 2) + 4 * Lhi;
          idx_hist[t][lvl] = code;
          const float sc = __uint_as_float(p & 0xFFFFFC00u) - 0.25f;  // r.e - e^2/2
          commit_acc += r2_sh[t] - 2.0f * sc;  // dist = ||r||^2 - 2*sc
        }
    }
    __syncthreads();  // idx_hist visible; e2_lds free for next level

    if (lvl < LEVELS - 1) {  // fp16 residual update + next-level r2
      r2p[0] = 0.f; r2p[1] = 0.f;
      #pragma unroll
      for (int mt = 0; mt < 2; ++mt) {
        const int qidx = idx_hist[wave * 64 + mt * 32 + Llo][lvl];
        const _Float16* qr = cb16 + (((size_t)lvl << 10) + qidx) * DIM + Lhi * 8;
        #pragma unroll
        for (int kk = 0; kk < 16; ++kk) {
          h8 q = *(const h8*)(qr + kk * 16);
          h8 r = af[mt][kk] - q;
          af[mt][kk] = r;
          r2p[mt] = sq8(r, r2p[mt]);
        }
      }
    }
  }

  // ---- epilogue: y = sum_l q_l, fp32-exact, fully coalesced ----
  float* yblk = out + (size_t)blockIdx.x * (TOKB * DIM);
  #pragma unroll 4
  for (int it = 0; it < 64; ++it) {
    const int f = it * 512 + tid * 4;
    const int t = f >> 8;  // wave-uniform token
    const int d = f & 255;
    const int4 qi = *(const int4*)&idx_hist[t][0];
    f4 q0 = *(const f4*)(cb32 + (size_t)qi.x * DIM + d);
    f4 q1 = *(const f4*)(cb32 + (size_t)(1024 + qi.y) * DIM + d);
    f4 q2 = *(const f4*)(cb32 + (size_t)(2048 + qi.z) * DIM + d);
    f4 q3 = *(const f4*)(cb32 + (size_t)(3072 + qi.w) * DIM + d);
    f4 yv = (q0 + q1) + (q2 + q3);
    *(f4*)(yblk + f) = yv;
  }

  // ---- commit: butterfly + one atomic per block ----
  #pragma unroll
  for (int off = 1; off < 64; off <<= 1) commit_acc += __shfl_xor(commit_acc, off, 64);
  if (lane == 0) csum_sh[wave] = commit_acc;
  __syncthreads();
  if (tid == 0) {
    atomicAdd(out + NELEM, (csum_sh[0] + csum_sh[1]) * (0.25f / 16777216.0f));  // BETA / (N*D)
  }
}

extern "C" void kernel_launch(void* const* d_in, const int* in_sizes, int n_in,
                              void* d_out, int out_size, void* d_ws, size_t ws_size,
                              hipStream_t stream) {
  const float* x = (const float*)d_in[0];
  const float* cb = (const float*)d_in[1];
  float* out = (float*)d_out;
  _Float16* cb16 = (_Float16*)d_ws;  // 2 MiB
  float* e2p = (float*)((char*)d_ws + (size_t)LEVELS * KCODES * DIM * sizeof(_Float16));

  rvq_prep<<<(LEVELS * KCODES) / 4, 256, 0, stream>>>(cb, cb16, e2p, out);
  rvq_main<<<NTOK / TOKB, 128, 0, stream>>>(x, cb, cb16, e2p, out);
}

// Round 2
// 278.127 us; speedup vs baseline: 1.0550x; 1.0550x over previous
//
#include <hip/hip_runtime.h>

#define DIM 256
#define KCODES 1024
#define LEVELS 4
#define CHUNK 64                 // codes per chunk
#define NCHUNK 16
#define TOKB 128                 // tokens per block (4 waves x 32)
#define NTOK 65536
#define NELEM (NTOK * DIM)

typedef _Float16 h8 __attribute__((ext_vector_type(8)));
typedef _Float16 h4 __attribute__((ext_vector_type(4)));
typedef _Float16 h2 __attribute__((ext_vector_type(2)));
typedef float f4 __attribute__((ext_vector_type(4)));
typedef float fx16 __attribute__((ext_vector_type(16)));
typedef unsigned int u32;

__device__ __forceinline__ void gload16(const void* g, void* l) {
  __builtin_amdgcn_global_load_lds(
      (const __attribute__((address_space(1))) void*)g,
      (__attribute__((address_space(3))) void*)l, 16, 0, 0);
}

// r2 accumulate over an h8 (v_dot2_f32_f16 when available: 4 instr vs 16)
__device__ __forceinline__ float sq8(h8 r, float acc) {
#if __has_builtin(__builtin_amdgcn_fdot2)
  #pragma unroll
  for (int j = 0; j < 4; ++j) {
    h2 p = {r[2 * j], r[2 * j + 1]};
    acc = __builtin_amdgcn_fdot2(p, p, acc, false);
  }
#else
  #pragma unroll
  for (int j = 0; j < 8; ++j) { float v = (float)r[j]; acc += v * v; }
#endif
  return acc;
}

// Phase 0: cb fp32 -> fp16; e2p = 0.25 - 0.5*||e||^2 (the +0.25 shift keeps all
// MFMA scores positive so raw float bits are unsigned-order-monotone -> 2-op
// argmax tracker). Also zeroes the commit accumulator (out is re-poisoned by
// the harness before every call).
__global__ __launch_bounds__(256) void rvq_prep(const float* __restrict__ cb,
                                                _Float16* __restrict__ cb16,
                                                float* __restrict__ e2p,
                                                float* __restrict__ out) {
  if (blockIdx.x == 0 && threadIdx.x == 0) out[NELEM] = 0.0f;
  const int row = blockIdx.x * 4 + (threadIdx.x >> 6);
  const int lane = threadIdx.x & 63;
  const float* src = cb + (size_t)row * DIM + lane * 4;
  f4 v = *(const f4*)src;
  h4 hv;
  hv[0] = (_Float16)v[0]; hv[1] = (_Float16)v[1];
  hv[2] = (_Float16)v[2]; hv[3] = (_Float16)v[3];
  *(h4*)(cb16 + (size_t)row * DIM + lane * 4) = hv;
  float s = v[0]*v[0] + v[1]*v[1] + v[2]*v[2] + v[3]*v[3];
  #pragma unroll
  for (int off = 32; off; off >>= 1) s += __shfl_xor(s, off, 64);
  if (lane == 0) e2p[row] = 0.25f - 0.5f * s;
}

// Main fused RVQ. Block = 4 waves x 32 tokens (one 32-row m-tile per wave,
// v_mfma_f32_32x32x16_f16) -> 2048 waves total = 2 waves/SIMD (round-1's
// 64-tok/wave halved wave count to 1/SIMD and lost 27% to exposed latency).
//
// LDS chunk is stored FRAGMENT-MAJOR: the B-frag for (nt,kk) occupies a
// contiguous 1 KB slot, lane l's 16 B granule at slot_base + l*16. Every
// ds_read_b128 is then uniform-base + lane*16 with an immediate offset:
// stride-1 (the HW coalesced fast path, zero bank conflicts per m134) and
// zero VALU address math. global_load_lds writes linearly, so the layout
// permutation lives entirely in the per-lane GLOBAL source address
// (linear-dest + pre-permuted-source, the only correct pairing): staging
// lane l fetches row nt*32+(l&31), dim-halves kk*16+(l>>5)*8 -- exactly
// what read-lane l consumes. Chunks are double-buffered, one barrier per
// chunk; prefetch for chunk g+1 is issued right after the barrier and
// drains a full compute phase later. Chunks are contiguous across levels.
__global__ __launch_bounds__(256, 2) void rvq_main(
    const float* __restrict__ x, const float* __restrict__ cb32,
    const _Float16* __restrict__ cb16, const float* __restrict__ e2p,
    float* __restrict__ out) {
  __shared__ __attribute__((aligned(16))) _Float16 clds[2][CHUNK * DIM];  // 64 KB
  __shared__ __attribute__((aligned(16))) float e2_lds[KCODES];           // 4 KB
  __shared__ __attribute__((aligned(16))) int idx_hist[TOKB][4];          // 2 KB
  __shared__ float r2_sh[TOKB];
  __shared__ float csum_sh[4];

  const int tid = threadIdx.x;
  const int wave = tid >> 6, lane = tid & 63;
  const int Llo = lane & 31, Lhi = lane >> 5;

  // Staging: 32 fragment-slots per chunk (2 nt x 16 kk), 8 per wave.
  // Wave w owns nt = w>>1, kk = (w&1)*8 .. +7.  Per call i:
  //   gsrc = chunk_base + (nt*32 + Llo)*512 + (kk0+i)*32 + Lhi*16
  //   ldst = clds[buf] + ((nt*16 + kk0 + i) << 10)        (+ lane*16 by DMA)
  const int snt = wave >> 1, sk0 = (wave & 1) << 3;
  const int sg_off = (snt * 32 + Llo) * 512 + (sk0 << 5) + (Lhi << 4);
  const int sl_off = (snt * 16 + sk0) << 10;
  const char* cb16b = (const char*)cb16;

  // issue chunk 0 staging immediately; it flies during the x-init loads
  {
    const char* gsrc = cb16b + sg_off;
    char* ldst = (char*)&clds[0][0] + sl_off;
    #pragma unroll
    for (int i = 0; i < 8; ++i) gload16(gsrc + i * 32, ldst + i * 1024);
  }

  // ---- init: x -> fp16 A-frags + r2 partial ----
  // A-frag (32x32x16): lane holds A[row = Llo][k = kk*16 + Lhi*8 + j].
  h8 af[16];
  float r2p = 0.f;
  const size_t tok0 = (size_t)blockIdx.x * TOKB + wave * 32;
  {
    const float* xr = x + (tok0 + Llo) * DIM + Lhi * 8;
    #pragma unroll
    for (int kk = 0; kk < 16; ++kk) {
      f4 a = *(const f4*)(xr + kk * 16);
      f4 b = *(const f4*)(xr + kk * 16 + 4);
      h8 h;
      #pragma unroll
      for (int j = 0; j < 4; ++j) { h[j] = (_Float16)a[j]; h[4 + j] = (_Float16)b[j]; }
      af[kk] = h;
      r2p = sq8(h, r2p);
    }
  }

  float commit_acc = 0.f;

  for (int lvl = 0; lvl < LEVELS; ++lvl) {
    // pre-update residual norms -> LDS (wave-local slots; commit identity)
    {
      float s = r2p + __shfl_xor(r2p, 32, 64);
      if (Lhi == 0) r2_sh[wave * 32 + Llo] = s;
    }
    // this level's shifted-e2 table (prev level's readers done: post-idx barrier)
    *(f4*)&e2_lds[tid * 4] = *(const f4*)(e2p + (lvl << 10) + tid * 4);

    u32 best[16];
    #pragma unroll
    for (int i = 0; i < 16; ++i) best[i] = 0u;

    for (int c = 0; c < NCHUNK; ++c) {
      __syncthreads();  // staging of chunk c (issued a full phase ago) visible
      {
        // prefetch chunk c+1 into the other buffer (contiguous across levels;
        // clamp keeps the last iteration in-bounds, write is harmless)
        const int gn = lvl * NCHUNK + c + 1;
        const char* gsrc = cb16b + ((size_t)(gn < 64 ? gn : 63) << 15) + sg_off;
        char* ldst = (char*)&clds[(c + 1) & 1][0] + sl_off;
        #pragma unroll
        for (int i = 0; i < 8; ++i) gload16(gsrc + i * 32, ldst + i * 1024);
      }

      const char* cbuf = (const char*)&clds[c & 1][0] + (lane << 4);
      const float e0 = e2_lds[c * 64 + Llo];        // 0.25 - ||e||^2/2
      const float e1 = e2_lds[c * 64 + 32 + Llo];
      fx16 acc0, acc1;
      #pragma unroll
      for (int i = 0; i < 16; ++i) { acc0[i] = e0; acc1[i] = e1; }
      // two independent 16-deep MFMA chains, stride-1 B reads (imm offsets)
      #pragma unroll
      for (int kk = 0; kk < 16; ++kk) {
        h8 b0 = *(const h8*)(cbuf + (kk << 10));
        h8 b1 = *(const h8*)(cbuf + ((16 + kk) << 10));
        acc0 = __builtin_amdgcn_mfma_f32_32x32x16_f16(af[kk], b0, acc0, 0, 0, 0);
        acc1 = __builtin_amdgcn_mfma_f32_32x32x16_f16(af[kk], b1, acc1, 0, 0, 0);
      }
      // scores all positive -> raw bits unsigned-monotone; pack
      // (bits & ~1023) | (1023-code): umax == argmax, smaller-index ties.
      // nt0/nt1 are DIFFERENT CODES for the SAME tokens -> fold into one best.
      const u32 invc0 = ((u32)(c * 64 + Llo)) ^ 1023u;
      const u32 invc1 = ((u32)(c * 64 + 32 + Llo)) ^ 1023u;
      #pragma unroll
      for (int i = 0; i < 16; ++i) {
        u32 p0 = (__float_as_uint(acc0[i]) & 0xFFFFFC00u) | invc0;
        if (p0 > best[i]) best[i] = p0;
        u32 p1 = (__float_as_uint(acc1[i]) & 0xFFFFFC00u) | invc1;
        if (p1 > best[i]) best[i] = p1;
      }
    }

    // reduce best across the 32 column (code) lanes
    #pragma unroll
    for (int i = 0; i < 16; ++i) {
      u32 b = best[i];
      #pragma unroll
      for (int off = 1; off < 32; off <<= 1) {
        u32 o = __shfl_xor(b, off, 32);
        if (o > b) b = o;
      }
      best[i] = b;
    }

    if (Llo == 0) {
      // C/D layout 32x32: col=Llo, row=(i&3)+8*(i>>2)+4*Lhi
      #pragma unroll
      for (int i = 0; i < 16; ++i) {
        const u32 p = best[i];
        const int code = (int)((p & 1023u) ^ 1023u);
        const int t = wave * 32 + (i & 3) + 8 * (i >> 2) + 4 * Lhi;
        idx_hist[t][lvl] = code;
        const float sc = __uint_as_float(p & 0xFFFFFC00u) - 0.25f;  // r.e - e^2/2
        commit_acc += r2_sh[t] - 2.0f * sc;  // dist = ||r||^2 - 2*sc
      }
    }
    __syncthreads();  // idx_hist visible; e2_lds free for next level

    if (lvl < LEVELS - 1) {  // fp16 residual update + next-level r2
      r2p = 0.f;
      const int qidx = idx_hist[wave * 32 + Llo][lvl];
      const _Float16* qr = cb16 + (((size_t)lvl << 10) + qidx) * DIM + Lhi * 8;
      #pragma unroll
      for (int kk = 0; kk < 16; ++kk) {
        h8 q = *(const h8*)(qr + kk * 16);
        h8 r = af[kk] - q;
        af[kk] = r;
        r2p = sq8(r, r2p);
      }
    }
  }

  // ---- epilogue: y = sum_l q_l, fp32-exact, fully coalesced ----
  float* yblk = out + (size_t)blockIdx.x * (TOKB * DIM);
  #pragma unroll 4
  for (int it = 0; it < 32; ++it) {
    const int f = it * 1024 + tid * 4;
    const int t = f >> 8;  // wave-uniform token
    const int d = f & 255;
    const int4 qi = *(const int4*)&idx_hist[t][0];
    f4 q0 = *(const f4*)(cb32 + (size_t)qi.x * DIM + d);
    f4 q1 = *(const f4*)(cb32 + (size_t)(1024 + qi.y) * DIM + d);
    f4 q2 = *(const f4*)(cb32 + (size_t)(2048 + qi.z) * DIM + d);
    f4 q3 = *(const f4*)(cb32 + (size_t)(3072 + qi.w) * DIM + d);
    f4 yv = (q0 + q1) + (q2 + q3);
    *(f4*)(yblk + f) = yv;
  }

  // ---- commit: butterfly + one atomic per block ----
  #pragma unroll
  for (int off = 1; off < 64; off <<= 1) commit_acc += __shfl_xor(commit_acc, off, 64);
  if (lane == 0) csum_sh[wave] = commit_acc;
  __syncthreads();
  if (tid == 0) {
    const float tot = csum_sh[0] + csum_sh[1] + csum_sh[2] + csum_sh[3];
    atomicAdd(out + NELEM, tot * (0.25f / 16777216.0f));  // BETA / (N*D)
  }
}

extern "C" void kernel_launch(void* const* d_in, const int* in_sizes, int n_in,
                              void* d_out, int out_size, void* d_ws, size_t ws_size,
                              hipStream_t stream) {
  const float* x = (const float*)d_in[0];
  const float* cb = (const float*)d_in[1];
  float* out = (float*)d_out;
  _Float16* cb16 = (_Float16*)d_ws;  // 2 MiB
  float* e2p = (float*)((char*)d_ws + (size_t)LEVELS * KCODES * DIM * sizeof(_Float16));

  rvq_prep<<<(LEVELS * KCODES) / 4, 256, 0, stream>>>(cb, cb16, e2p, out);
  rvq_main<<<NTOK / TOKB, 256, 0, stream>>>(x, cb, cb16, e2p, out);
}

// Round 3
// 261.046 us; speedup vs baseline: 1.1240x; 1.0654x over previous
//
#include <hip/hip_runtime.h>

#define DIM 256
#define KCODES 1024
#define LEVELS 4
#define CHUNK 64                 // codes per chunk
#define NCHUNK 16
#define TOKB 128                 // tokens per block (4 waves x 32)
#define NTOK 65536
#define NELEM (NTOK * DIM)

typedef _Float16 h8 __attribute__((ext_vector_type(8)));
typedef _Float16 h4 __attribute__((ext_vector_type(4)));
typedef _Float16 h2 __attribute__((ext_vector_type(2)));
typedef float f4 __attribute__((ext_vector_type(4)));
typedef unsigned int u32;

__device__ __forceinline__ void gload16(const void* g, void* l) {
  __builtin_amdgcn_global_load_lds(
      (const __attribute__((address_space(1))) void*)g,
      (__attribute__((address_space(3))) void*)l, 16, 0, 0);
}

// r2 accumulate over an h8 (v_dot2_f32_f16 when available: 4 instr vs 16)
__device__ __forceinline__ float sq8(h8 r, float acc) {
#if __has_builtin(__builtin_amdgcn_fdot2)
  #pragma unroll
  for (int j = 0; j < 4; ++j) {
    h2 p = {r[2 * j], r[2 * j + 1]};
    acc = __builtin_amdgcn_fdot2(p, p, acc, false);
  }
#else
  #pragma unroll
  for (int j = 0; j < 8; ++j) { float v = (float)r[j]; acc += v * v; }
#endif
  return acc;
}

// Phase 0: cb fp32 -> fp16; e2p = 0.25 - 0.5*||e||^2 (the +0.25 shift keeps all
// MFMA scores positive so raw float bits are unsigned-order-monotone -> 2-op
// argmax tracker). Also zeroes the commit accumulator (out is re-poisoned by
// the harness before every call).
__global__ __launch_bounds__(256) void rvq_prep(const float* __restrict__ cb,
                                                _Float16* __restrict__ cb16,
                                                float* __restrict__ e2p,
                                                float* __restrict__ out) {
  if (blockIdx.x == 0 && threadIdx.x == 0) out[NELEM] = 0.0f;
  const int row = blockIdx.x * 4 + (threadIdx.x >> 6);
  const int lane = threadIdx.x & 63;
  const float* src = cb + (size_t)row * DIM + lane * 4;
  f4 v = *(const f4*)src;
  h4 hv;
  hv[0] = (_Float16)v[0]; hv[1] = (_Float16)v[1];
  hv[2] = (_Float16)v[2]; hv[3] = (_Float16)v[3];
  *(h4*)(cb16 + (size_t)row * DIM + lane * 4) = hv;
  float s = v[0]*v[0] + v[1]*v[1] + v[2]*v[2] + v[3]*v[3];
  #pragma unroll
  for (int off = 32; off; off >>= 1) s += __shfl_xor(s, off, 64);
  if (lane == 0) e2p[row] = 0.25f - 0.5f * s;
}

// Main fused RVQ. Round-0 schedule (4 waves x 32 tokens, 2 m-tiles of 16,
// v_mfma_f32_16x16x32_f16, 8 independent 8-deep accumulator chains per wave
// -> proven 176 us) + round-2's FRAGMENT-MAJOR conflict-free LDS layout:
//
// The B-frag for (nt,kk) occupies a contiguous 1 KB slot at (nt*8+kk)<<10;
// lane l's 16 B granule at slot + l*16. Every ds_read_b128 is uniform-base +
// lane*16 with a compile-time immediate: stride-1 (2-way aliasing = free per
// m136; verified 1.68e7 -> 3.7e4 conflicts in round 2) and zero per-read VALU
// address math. global_load_lds writes linearly (base + lane*16), so the
// permutation lives entirely in the per-lane GLOBAL source address (the only
// correct pairing): staging lane l (col=l&15, quad=l>>4) fetches row
// w*16+col, 16B-granule i*4+quad -- exactly what read-lane l consumes from
// slot (w,i). Chunks double-buffered, one barrier per chunk; prefetch for
// chunk c+1 issued right after the barrier drains a full compute phase later
// (implicit vmcnt(0) at the next barrier). Chunks contiguous across levels.
__global__ __launch_bounds__(256, 2) void rvq_main(
    const float* __restrict__ x, const float* __restrict__ cb32,
    const _Float16* __restrict__ cb16, const float* __restrict__ e2p,
    float* __restrict__ out) {
  __shared__ __attribute__((aligned(16))) _Float16 clds[2][CHUNK * DIM];  // 64 KB
  __shared__ __attribute__((aligned(16))) float e2_lds[KCODES];           // 4 KB
  __shared__ __attribute__((aligned(16))) int idx_hist[TOKB][4];          // 2 KB
  __shared__ float r2_sh[TOKB];
  __shared__ float csum_sh[4];

  const int tid = threadIdx.x;
  const int wave = tid >> 6, lane = tid & 63;
  const int col = lane & 15, quad = lane >> 4;

  // Staging: 32 fragment-slots per chunk (4 nt x 8 kk), wave w owns nt=w,
  // kk=i (8 gload16 calls). Per call i:
  //   gsrc = chunk_base + (w*16 + col)*512 + (i*4 + quad)*16
  //   ldst = clds[buf] + ((w*8 + i) << 10)        (+ lane*16 by the DMA)
  const int sg_off = (wave * 16 + col) * 512 + (quad << 4);
  const int sl_off = wave * 8192;
  const char* cb16b = (const char*)cb16;

  // issue chunk 0 staging immediately; it flies during the x-init loads
  {
    const char* gsrc = cb16b + sg_off;
    char* ldst = (char*)&clds[0][0] + sl_off;
    #pragma unroll
    for (int i = 0; i < 8; ++i) gload16(gsrc + i * 64, ldst + i * 1024);
  }

  // ---- init: x -> fp16 A-frags + r2 partials ----
  // A-frag (16x16x32): lane holds A[row=col][k = kk*32 + quad*8 + j].
  h8 af[2][8];
  float r2p[2] = {0.f, 0.f};
  const size_t tok0 = (size_t)blockIdx.x * TOKB + wave * 32;
  #pragma unroll
  for (int mt = 0; mt < 2; ++mt) {
    const float* xr = x + (tok0 + mt * 16 + col) * DIM + quad * 8;
    #pragma unroll
    for (int kk = 0; kk < 8; ++kk) {
      f4 a = *(const f4*)(xr + kk * 32);
      f4 b = *(const f4*)(xr + kk * 32 + 4);
      h8 h;
      #pragma unroll
      for (int j = 0; j < 4; ++j) { h[j] = (_Float16)a[j]; h[4 + j] = (_Float16)b[j]; }
      af[mt][kk] = h;
      r2p[mt] = sq8(h, r2p[mt]);
    }
  }

  float commit_acc = 0.f;

  for (int lvl = 0; lvl < LEVELS; ++lvl) {
    // pre-update residual norms -> LDS (wave-local slots; commit identity)
    #pragma unroll
    for (int mt = 0; mt < 2; ++mt) {
      float s = r2p[mt];
      s += __shfl_xor(s, 16, 64);
      s += __shfl_xor(s, 32, 64);
      if (quad == 0) r2_sh[wave * 32 + mt * 16 + col] = s;
    }
    // this level's shifted-e2 table (prev level's readers done: post-idx barrier)
    *(f4*)&e2_lds[tid * 4] = *(const f4*)(e2p + (lvl << 10) + tid * 4);

    u32 best[2][4];
    #pragma unroll
    for (int mt = 0; mt < 2; ++mt)
      #pragma unroll
      for (int i = 0; i < 4; ++i) best[mt][i] = 0u;

    for (int c = 0; c < NCHUNK; ++c) {
      __syncthreads();  // staging of chunk c (issued a full phase ago) visible
      {
        // prefetch chunk c+1 into the other buffer (contiguous across levels;
        // clamp keeps the last iteration in-bounds, write is harmless)
        const int gn = lvl * NCHUNK + c + 1;
        const char* gsrc = cb16b + ((size_t)(gn < 64 ? gn : 63) << 15) + sg_off;
        char* ldst = (char*)&clds[(c + 1) & 1][0] + sl_off;
        #pragma unroll
        for (int i = 0; i < 8; ++i) gload16(gsrc + i * 64, ldst + i * 1024);
      }

      const char* cbuf = (const char*)&clds[c & 1][0] + (lane << 4);
      #pragma unroll
      for (int nt = 0; nt < 4; ++nt) {
        const int code0 = c * 64 + nt * 16;
        const float e2v = e2_lds[code0 + col];  // 0.25 - ||e||^2/2
        f4 acc0 = {e2v, e2v, e2v, e2v};
        f4 acc1 = acc0;
        #pragma unroll
        for (int kk = 0; kk < 8; ++kk) {
          h8 b = *(const h8*)(cbuf + ((nt * 8 + kk) << 10));  // imm offset, stride-1
          acc0 = __builtin_amdgcn_mfma_f32_16x16x32_f16(af[0][kk], b, acc0, 0, 0, 0);
          acc1 = __builtin_amdgcn_mfma_f32_16x16x32_f16(af[1][kk], b, acc1, 0, 0, 0);
        }
        // scores all positive -> raw bits unsigned-monotone; pack
        // (bits & ~1023) | (1023-code): umax == argmax, smaller-index ties
        const u32 invc = (u32)(code0 + col) ^ 1023u;
        #pragma unroll
        for (int i = 0; i < 4; ++i) {
          u32 p0 = (__float_as_uint(acc0[i]) & 0xFFFFFC00u) | invc;
          if (p0 > best[0][i]) best[0][i] = p0;
          u32 p1 = (__float_as_uint(acc1[i]) & 0xFFFFFC00u) | invc;
          if (p1 > best[1][i]) best[1][i] = p1;
        }
      }
    }

    // reduce best across the 16 column lanes
    #pragma unroll
    for (int mt = 0; mt < 2; ++mt)
      #pragma unroll
      for (int i = 0; i < 4; ++i) {
        u32 b = best[mt][i];
        #pragma unroll
        for (int off = 1; off < 16; off <<= 1) {
          u32 o = __shfl_xor(b, off, 16);
          if (o > b) b = o;
        }
        best[mt][i] = b;
      }

    if (col == 0) {
      // C/D layout 16x16: col=lane&15, row=quad*4+i
      #pragma unroll
      for (int mt = 0; mt < 2; ++mt)
        #pragma unroll
        for (int i = 0; i < 4; ++i) {
          const u32 p = best[mt][i];
          const int code = (int)((p & 1023u) ^ 1023u);
          const int t = wave * 32 + mt * 16 + quad * 4 + i;
          idx_hist[t][lvl] = code;
          const float sc = __uint_as_float(p & 0xFFFFFC00u) - 0.25f;  // r.e - e^2/2
          commit_acc += r2_sh[t] - 2.0f * sc;  // dist = ||r||^2 - 2*sc
        }
    }
    __syncthreads();  // idx_hist visible to all; e2_lds free for next level

    if (lvl < LEVELS - 1) {  // fp16 residual update + next-level r2
      r2p[0] = 0.f; r2p[1] = 0.f;
      #pragma unroll
      for (int mt = 0; mt < 2; ++mt) {
        const int qidx = idx_hist[wave * 32 + mt * 16 + col][lvl];
        const _Float16* qr = cb16 + (((size_t)lvl << 10) + qidx) * DIM + quad * 8;
        #pragma unroll
        for (int kk = 0; kk < 8; ++kk) {
          h8 q = *(const h8*)(qr + kk * 32);
          h8 r = af[mt][kk] - q;
          af[mt][kk] = r;
          r2p[mt] = sq8(r, r2p[mt]);
        }
      }
    }
  }

  // ---- epilogue: y = sum_l q_l, fp32-exact, fully coalesced ----
  float* yblk = out + (size_t)blockIdx.x * (TOKB * DIM);
  #pragma unroll 4
  for (int it = 0; it < 32; ++it) {
    const int f = it * 1024 + tid * 4;
    const int t = f >> 8;  // wave-uniform token
    const int d = f & 255;
    const int4 qi = *(const int4*)&idx_hist[t][0];
    f4 q0 = *(const f4*)(cb32 + (size_t)qi.x * DIM + d);
    f4 q1 = *(const f4*)(cb32 + (size_t)(1024 + qi.y) * DIM + d);
    f4 q2 = *(const f4*)(cb32 + (size_t)(2048 + qi.z) * DIM + d);
    f4 q3 = *(const f4*)(cb32 + (size_t)(3072 + qi.w) * DIM + d);
    f4 yv = (q0 + q1) + (q2 + q3);
    *(f4*)(yblk + f) = yv;
  }

  // ---- commit: butterfly + one atomic per block ----
  #pragma unroll
  for (int off = 1; off < 64; off <<= 1) commit_acc += __shfl_xor(commit_acc, off, 64);
  if (lane == 0) csum_sh[wave] = commit_acc;
  __syncthreads();
  if (tid == 0) {
    const float tot = csum_sh[0] + csum_sh[1] + csum_sh[2] + csum_sh[3];
    atomicAdd(out + NELEM, tot * (0.25f / 16777216.0f));  // BETA / (N*D)
  }
}

extern "C" void kernel_launch(void* const* d_in, const int* in_sizes, int n_in,
                              void* d_out, int out_size, void* d_ws, size_t ws_size,
                              hipStream_t stream) {
  const float* x = (const float*)d_in[0];
  const float* cb = (const float*)d_in[1];
  float* out = (float*)d_out;
  _Float16* cb16 = (_Float16*)d_ws;  // 2 MiB
  float* e2p = (float*)((char*)d_ws + (size_t)LEVELS * KCODES * DIM * sizeof(_Float16));

  rvq_prep<<<(LEVELS * KCODES) / 4, 256, 0, stream>>>(cb, cb16, e2p, out);
  rvq_main<<<NTOK / TOKB, 256, 0, stream>>>(x, cb, cb16, e2p, out);
}

// Round 4
// 253.901 us; speedup vs baseline: 1.1557x; 1.0281x over previous
//
#include <hip/hip_runtime.h>

#define DIM 256
#define KCODES 1024
#define LEVELS 4
#define CHUNK 64                 // codes per chunk
#define NCHUNK 16
#define TOKB 128                 // tokens per block (4 waves x 32)
#define NTOK 65536
#define NELEM (NTOK * DIM)

typedef _Float16 h8 __attribute__((ext_vector_type(8)));
typedef _Float16 h4 __attribute__((ext_vector_type(4)));
typedef _Float16 h2 __attribute__((ext_vector_type(2)));
typedef float f4 __attribute__((ext_vector_type(4)));
typedef unsigned int u32;

__device__ __forceinline__ void gload16(const void* g, void* l) {
  __builtin_amdgcn_global_load_lds(
      (const __attribute__((address_space(1))) void*)g,
      (__attribute__((address_space(3))) void*)l, 16, 0, 0);
}

// r2 accumulate over an h8 (v_dot2_f32_f16 when available: 4 instr vs 16)
__device__ __forceinline__ float sq8(h8 r, float acc) {
#if __has_builtin(__builtin_amdgcn_fdot2)
  #pragma unroll
  for (int j = 0; j < 4; ++j) {
    h2 p = {r[2 * j], r[2 * j + 1]};
    acc = __builtin_amdgcn_fdot2(p, p, acc, false);
  }
#else
  #pragma unroll
  for (int j = 0; j < 8; ++j) { float v = (float)r[j]; acc += v * v; }
#endif
  return acc;
}

// FRAGMENT-MAJOR cb16 global layout (written by prep, consumed linearly by
// main's staging): global code row G (0..4095), 16-B granule g (0..31, i.e.
// k-elements g*8..g*8+7) lives at byte
//   ((G>>6)<<15)            chunk of 64 codes, 32 KB
// + (((G>>4)&3)<<13)        nt (16-code group) within chunk, 8 KB
// + ((g>>2)<<10)            kk slot (k-block of 32 elems), 1 KB
// + (((g&3)*16 + (G&15))<<4)  lane position quad*16+col within the slot
// With this, the B-frag for (nt,kk) is one contiguous 1 KB block in LANE
// ORDER: staging is a pure linear copy (gsrc = slot_base + lane*16 ->
// ldst + lane*16, fully coalesced 1 KB/instruction), and every compute-side
// ds_read_b128 is uniform-base + lane*16 + immediate (stride-1, conflict-
// free: verified 1.68e7 -> 2.5e4 conflict-cycles in rounds 2/3).

// Phase 0: cb fp32 -> fp16 (fragment-major); e2p = 0.25 - 0.5*||e||^2 (the
// +0.25 shift keeps all MFMA scores positive so raw float bits are unsigned-
// order-monotone -> 2-op argmax tracker). Also zeroes the commit accumulator
// (out is re-poisoned by the harness before every call).
__global__ __launch_bounds__(256) void rvq_prep(const float* __restrict__ cb,
                                                _Float16* __restrict__ cb16,
                                                float* __restrict__ e2p,
                                                float* __restrict__ out) {
  if (blockIdx.x == 0 && threadIdx.x == 0) out[NELEM] = 0.0f;
  const int row = blockIdx.x * 4 + (threadIdx.x >> 6);
  const int lane = threadIdx.x & 63;
  const float* src = cb + (size_t)row * DIM + lane * 4;
  f4 v = *(const f4*)src;
  h4 hv;
  hv[0] = (_Float16)v[0]; hv[1] = (_Float16)v[1];
  hv[2] = (_Float16)v[2]; hv[3] = (_Float16)v[3];
  // lane covers elements lane*4..+3 = half (lane&1) of granule g = lane>>1
  const int g = lane >> 1;
  char* dst = (char*)cb16 + (((size_t)row >> 6) << 15) + (((row >> 4) & 3) << 13) +
              ((g >> 2) << 10) + ((((g & 3) << 4) + (row & 15)) << 4) +
              ((lane & 1) << 3);
  *(h4*)dst = hv;
  float s = v[0]*v[0] + v[1]*v[1] + v[2]*v[2] + v[3]*v[3];
  #pragma unroll
  for (int off = 32; off; off >>= 1) s += __shfl_xor(s, off, 64);
  if (lane == 0) e2p[row] = 0.25f - 0.5f * s;
}

// Main fused RVQ. Round-0 schedule (4 waves x 32 tokens, 2 m-tiles of 16,
// v_mfma_f32_16x16x32_f16, 8 independent 8-deep accumulator chains per wave)
// + conflict-free fragment-major LDS reads (round 3) + fully-linear staging
// (this round: cb16 pre-permuted, so staging source is contiguous 1 KB per
// gload16 -- round 3's 16x64B scattered source was the 22 us regression).
// Chunks double-buffered, one barrier per chunk; prefetch for chunk c+1 is
// issued right after the barrier and drains a full compute phase later.
// Chunks contiguous across levels, so prefetch covers level boundaries.
__global__ __launch_bounds__(256, 2) void rvq_main(
    const float* __restrict__ x, const float* __restrict__ cb32,
    const _Float16* __restrict__ cb16, const float* __restrict__ e2p,
    float* __restrict__ out) {
  __shared__ __attribute__((aligned(16))) _Float16 clds[2][CHUNK * DIM];  // 64 KB
  __shared__ __attribute__((aligned(16))) float e2_lds[KCODES];           // 4 KB
  __shared__ __attribute__((aligned(16))) int idx_hist[TOKB][4];          // 2 KB
  __shared__ float r2_sh[TOKB];
  __shared__ float csum_sh[4];

  const int tid = threadIdx.x;
  const int wave = tid >> 6, lane = tid & 63;
  const int col = lane & 15, quad = lane >> 4;

  // Staging: 32 slots/chunk (1 KB each); wave w copies slots w*8..w*8+7.
  // Linear copy: gsrc = chunk_base + slot*1024 + lane*16, ldst = slot*1024.
  const int sl_off = wave * 8192;
  const int sg0 = sl_off + (lane << 4);
  const char* cb16b = (const char*)cb16;

  // issue chunk 0 staging immediately; it flies during the x-init loads
  {
    const char* gsrc = cb16b + sg0;
    char* ldst = (char*)&clds[0][0] + sl_off;
    #pragma unroll
    for (int i = 0; i < 8; ++i) gload16(gsrc + i * 1024, ldst + i * 1024);
  }

  // ---- init: x -> fp16 A-frags + r2 partials ----
  // A-frag (16x16x32): lane holds A[row=col][k = kk*32 + quad*8 + j].
  h8 af[2][8];
  float r2p[2] = {0.f, 0.f};
  const size_t tok0 = (size_t)blockIdx.x * TOKB + wave * 32;
  #pragma unroll
  for (int mt = 0; mt < 2; ++mt) {
    const float* xr = x + (tok0 + mt * 16 + col) * DIM + quad * 8;
    #pragma unroll
    for (int kk = 0; kk < 8; ++kk) {
      f4 a = *(const f4*)(xr + kk * 32);
      f4 b = *(const f4*)(xr + kk * 32 + 4);
      h8 h;
      #pragma unroll
      for (int j = 0; j < 4; ++j) { h[j] = (_Float16)a[j]; h[4 + j] = (_Float16)b[j]; }
      af[mt][kk] = h;
      r2p[mt] = sq8(h, r2p[mt]);
    }
  }

  float commit_acc = 0.f;

  for (int lvl = 0; lvl < LEVELS; ++lvl) {
    // pre-update residual norms -> LDS (wave-local slots; commit identity)
    #pragma unroll
    for (int mt = 0; mt < 2; ++mt) {
      float s = r2p[mt];
      s += __shfl_xor(s, 16, 64);
      s += __shfl_xor(s, 32, 64);
      if (quad == 0) r2_sh[wave * 32 + mt * 16 + col] = s;
    }
    // this level's shifted-e2 table (prev level's readers done: post-idx barrier)
    *(f4*)&e2_lds[tid * 4] = *(const f4*)(e2p + (lvl << 10) + tid * 4);

    u32 best[2][4];
    #pragma unroll
    for (int mt = 0; mt < 2; ++mt)
      #pragma unroll
      for (int i = 0; i < 4; ++i) best[mt][i] = 0u;

    for (int c = 0; c < NCHUNK; ++c) {
      __syncthreads();  // staging of chunk c (issued a full phase ago) visible
      {
        // prefetch chunk c+1 into the other buffer (contiguous across levels;
        // clamp keeps the last iteration in-bounds, write is harmless)
        const int gn = lvl * NCHUNK + c + 1;
        const char* gsrc = cb16b + ((size_t)(gn < 64 ? gn : 63) << 15) + sg0;
        char* ldst = (char*)&clds[(c + 1) & 1][0] + sl_off;
        #pragma unroll
        for (int i = 0; i < 8; ++i) gload16(gsrc + i * 1024, ldst + i * 1024);
      }

      const char* cbuf = (const char*)&clds[c & 1][0] + (lane << 4);
      #pragma unroll
      for (int nt = 0; nt < 4; ++nt) {
        const int code0 = c * 64 + nt * 16;
        const float e2v = e2_lds[code0 + col];  // 0.25 - ||e||^2/2
        f4 acc0 = {e2v, e2v, e2v, e2v};
        f4 acc1 = acc0;
        #pragma unroll
        for (int kk = 0; kk < 8; ++kk) {
          h8 b = *(const h8*)(cbuf + ((nt * 8 + kk) << 10));  // imm offset, stride-1
          acc0 = __builtin_amdgcn_mfma_f32_16x16x32_f16(af[0][kk], b, acc0, 0, 0, 0);
          acc1 = __builtin_amdgcn_mfma_f32_16x16x32_f16(af[1][kk], b, acc1, 0, 0, 0);
        }
        // scores all positive -> raw bits unsigned-monotone; pack
        // (bits & ~1023) | (1023-code): umax == argmax, smaller-index ties
        const u32 invc = (u32)(code0 + col) ^ 1023u;
        #pragma unroll
        for (int i = 0; i < 4; ++i) {
          u32 p0 = (__float_as_uint(acc0[i]) & 0xFFFFFC00u) | invc;
          if (p0 > best[0][i]) best[0][i] = p0;
          u32 p1 = (__float_as_uint(acc1[i]) & 0xFFFFFC00u) | invc;
          if (p1 > best[1][i]) best[1][i] = p1;
        }
      }
    }

    // reduce best across the 16 column lanes
    #pragma unroll
    for (int mt = 0; mt < 2; ++mt)
      #pragma unroll
      for (int i = 0; i < 4; ++i) {
        u32 b = best[mt][i];
        #pragma unroll
        for (int off = 1; off < 16; off <<= 1) {
          u32 o = __shfl_xor(b, off, 16);
          if (o > b) b = o;
        }
        best[mt][i] = b;
      }

    if (col == 0) {
      // C/D layout 16x16: col=lane&15, row=quad*4+i
      #pragma unroll
      for (int mt = 0; mt < 2; ++mt)
        #pragma unroll
        for (int i = 0; i < 4; ++i) {
          const u32 p = best[mt][i];
          const int code = (int)((p & 1023u) ^ 1023u);
          const int t = wave * 32 + mt * 16 + quad * 4 + i;
          idx_hist[t][lvl] = code;
          const float sc = __uint_as_float(p & 0xFFFFFC00u) - 0.25f;  // r.e - e^2/2
          commit_acc += r2_sh[t] - 2.0f * sc;  // dist = ||r||^2 - 2*sc
        }
    }
    __syncthreads();  // idx_hist visible to all; e2_lds free for next level

    if (lvl < LEVELS - 1) {  // fp16 residual update + next-level r2
      r2p[0] = 0.f; r2p[1] = 0.f;
      #pragma unroll
      for (int mt = 0; mt < 2; ++mt) {
        const int qidx = idx_hist[wave * 32 + mt * 16 + col][lvl];
        // fragment-major address of code row G, this thread's quad granules
        const int G = (lvl << 10) + qidx;
        const char* qbase = cb16b + ((size_t)(G >> 6) << 15) + (((G >> 4) & 3) << 13) +
                            ((quad * 16 + (G & 15)) << 4);
        #pragma unroll
        for (int kk = 0; kk < 8; ++kk) {
          h8 q = *(const h8*)(qbase + (kk << 10));
          h8 r = af[mt][kk] - q;
          af[mt][kk] = r;
          r2p[mt] = sq8(r, r2p[mt]);
        }
      }
    }
  }

  // ---- epilogue: y = sum_l q_l, fp32-exact, fully coalesced ----
  float* yblk = out + (size_t)blockIdx.x * (TOKB * DIM);
  #pragma unroll 4
  for (int it = 0; it < 32; ++it) {
    const int f = it * 1024 + tid * 4;
    const int t = f >> 8;  // wave-uniform token
    const int d = f & 255;
    const int4 qi = *(const int4*)&idx_hist[t][0];
    f4 q0 = *(const f4*)(cb32 + (size_t)qi.x * DIM + d);
    f4 q1 = *(const f4*)(cb32 + (size_t)(1024 + qi.y) * DIM + d);
    f4 q2 = *(const f4*)(cb32 + (size_t)(2048 + qi.z) * DIM + d);
    f4 q3 = *(const f4*)(cb32 + (size_t)(3072 + qi.w) * DIM + d);
    f4 yv = (q0 + q1) + (q2 + q3);
    *(f4*)(yblk + f) = yv;
  }

  // ---- commit: butterfly + one atomic per block ----
  #pragma unroll
  for (int off = 1; off < 64; off <<= 1) commit_acc += __shfl_xor(commit_acc, off, 64);
  if (lane == 0) csum_sh[wave] = commit_acc;
  __syncthreads();
  if (tid == 0) {
    const float tot = csum_sh[0] + csum_sh[1] + csum_sh[2] + csum_sh[3];
    atomicAdd(out + NELEM, tot * (0.25f / 16777216.0f));  // BETA / (N*D)
  }
}

extern "C" void kernel_launch(void* const* d_in, const int* in_sizes, int n_in,
                              void* d_out, int out_size, void* d_ws, size_t ws_size,
                              hipStream_t stream) {
  const float* x = (const float*)d_in[0];
  const float* cb = (const float*)d_in[1];
  float* out = (float*)d_out;
  _Float16* cb16 = (_Float16*)d_ws;  // 2 MiB, fragment-major
  float* e2p = (float*)((char*)d_ws + (size_t)LEVELS * KCODES * DIM * sizeof(_Float16));

  rvq_prep<<<(LEVELS * KCODES) / 4, 256, 0, stream>>>(cb, cb16, e2p, out);
  rvq_main<<<NTOK / TOKB, 256, 0, stream>>>(x, cb, cb16, e2p, out);
}